// Round 2
// baseline (64.057 us; speedup 1.0000x reference)
//
#include <hip/hip_runtime.h>
#include <math.h>

// Problem constants (from reference)
#define T_LEN   200
#define B_SZ    4096
#define V_SZ    100000
#define PAD_TOK 1

// Geometry: G columns/block, 512 threads, compact CAS hash set per column.
// LDS = 8*512*4 = 16 KB (+acc) -> 2 resident blocks/CU (16 waves/CU),
// 512 blocks over 256 CUs = exactly 2 blocks/CU of work (no tail).
#define G        8
#define NBLOCKS  (B_SZ / G)            // 512
#define NTHREADS 512
#define HBITS    9
#define HSIZE    (1 << HBITS)          // 512 entries/column, load 200/512
#define ROWS_PER_ITER (NTHREADS / G)   // 64
#define MAX_K    ((T_LEN + ROWS_PER_ITER - 1) / ROWS_PER_ITER)  // 4

__global__ __launch_bounds__(NTHREADS) void bow_sigmoid_kernel(
    const int*   __restrict__ text,   // [T, B] int32 token ids
    const float* __restrict__ W,      // [1, V]
    const float* __restrict__ bias,   // [1]
    float*       __restrict__ out)    // [B, 1]
{
    __shared__ __align__(16) int hset[G][HSIZE];   // 16 KB
    __shared__ float acc[G];

    const int tid = threadIdx.x;
    const int blk = blockIdx.x;

    // XCD swizzle: blocks round-robin over 8 XCDs; keep column ranges
    // contiguous per XCD so text cache lines stay in one XCD's L2.
    const int g  = (blk & 7) * (NBLOCKS / 8) + (blk >> 3);
    const int b0 = g * G;

    const int c  = tid & (G - 1);   // column within group, 0..7
    const int t0 = tid >> 3;        // starting row, 0..63

    // Phase 0: issue ALL token loads first (independent, latency overlaps
    // the LDS clear below).
    int toks[MAX_K];
    #pragma unroll
    for (int k = 0; k < MAX_K; ++k) {
        const int t = t0 + k * ROWS_PER_ITER;
        toks[k] = (t < T_LEN) ? text[t * B_SZ + b0 + c] : PAD_TOK;
    }

    // Phase 1: clear hash sets (sentinel -1; token 0 is valid) + acc.
    // 4096 words = 1024 int4 stores over 512 threads = 2 per thread.
    int4* hs4 = (int4*)&hset[0][0];
    #pragma unroll
    for (int i = tid; i < (G * HSIZE) / 4; i += NTHREADS)
        hs4[i] = make_int4(-1, -1, -1, -1);
    if (tid < G) acc[tid] = 0.0f;

    // Phase 2: issue ALL W gathers unconditionally (branch-free address so
    // the loads cluster here, BEFORE the barrier and the CAS loop — their
    // ~200-900 cy latency overlaps clear + barrier + dedup instead of being
    // gated behind each LDS atomic's return).
    float wv[MAX_K];
    #pragma unroll
    for (int k = 0; k < MAX_K; ++k) {
        const int tok = toks[k];
        wv[k] = W[(tok == PAD_TOK) ? 0 : tok];
    }

    __syncthreads();

    // Phase 3: dedup via CAS hash; gathers already in flight/registers.
    float sum = 0.0f;
    #pragma unroll
    for (int k = 0; k < MAX_K; ++k) {
        const int tok = toks[k];
        if (tok == PAD_TOK) continue;
        unsigned h = ((unsigned)tok * 2654435761u) >> (32 - HBITS);
        for (;;) {
            const int old = atomicCAS(&hset[c][h], -1, tok);
            if (old == -1) { sum += wv[k]; break; }  // first insert
            if (old == tok) break;                    // duplicate: skip
            h = (h + 1) & (HSIZE - 1);
        }
    }

    // Phase 4: reduce across the 8 lanes of each wave sharing column c
    // (lanes c, c+8, ..., c+56): butterfly over lane-id bits 3..5.
    sum += __shfl_xor(sum, 8, 64);
    sum += __shfl_xor(sum, 16, 64);
    sum += __shfl_xor(sum, 32, 64);
    if ((tid & 63) < G) atomicAdd(&acc[c], sum);   // one add per wave per column
    __syncthreads();

    if (tid < G) {
        const float s = acc[tid] + bias[0];
        out[b0 + tid] = 1.0f / (1.0f + expf(-s));
    }
}

extern "C" void kernel_launch(void* const* d_in, const int* in_sizes, int n_in,
                              void* d_out, int out_size, void* d_ws, size_t ws_size,
                              hipStream_t stream) {
    const int*   text = (const int*)d_in[0];    // [200, 4096] int32
    const float* W    = (const float*)d_in[1];  // [1, 100000]
    const float* bias = (const float*)d_in[2];  // [1]
    float*       out  = (float*)d_out;          // [4096, 1]

    bow_sigmoid_kernel<<<NBLOCKS, NTHREADS, 0, stream>>>(text, W, bias, out);
}